// Round 6
// baseline (620.160 us; speedup 1.0000x reference)
//
#include <hip/hip_runtime.h>
#include <hip/hip_fp16.h>

#define HH 8
#define BB 256
#define SS 64
#define EE 256
#define DH 32
#define DD 2048   // S*d

typedef _Float16 f16x8 __attribute__((ext_vector_type(8)));
typedef _Float16 f16x4 __attribute__((ext_vector_type(4)));
typedef _Float16 f16x2 __attribute__((ext_vector_type(2)));
typedef float f32x4v __attribute__((ext_vector_type(4)));

#define BM 256
#define BN 64
#define BK 64
#define LDK 72   // Asm padded stride (halfs): 144B rows -> 2-way max on frag reads (free)

__device__ inline void gload_lds16(const void* g, void* l) {
    __builtin_amdgcn_global_load_lds((const __attribute__((address_space(1))) void*)g,
                                     (__attribute__((address_space(3))) void*)l, 16, 0, 0);
}

// 768 blocks = 3 blocks/CU exactly. Weights via global_load_lds (async, fp32,
// XOR-swizzled via pre-swizzled global source); activations reg-staged fp16.
__global__ __launch_bounds__(512, 6)
void qkv_kernel(const float* __restrict__ dec, const float* __restrict__ enc,
                const float* __restrict__ WQ, const float* __restrict__ bQ,
                const float* __restrict__ WK, const float* __restrict__ bK,
                const float* __restrict__ WV, const float* __restrict__ bV,
                __half* __restrict__ qkv)
{
    __shared__ _Float16 Asm[BM][LDK];   // 36 KB
    __shared__ float    Bsm[BN * BK];   // 16 KB, rows of 256B, XOR-swizzled

    const int z = blockIdx.z;
    const int p = z >> 3;               // 0:Q 1:K 2:V
    const int h = z & 7;
    const float* __restrict__ x    = (p == 0) ? dec : enc;
    const float* __restrict__ W    = (p == 0) ? WQ : (p == 1) ? WK : WV;
    const float* __restrict__ bias = (p == 0) ? bQ : (p == 1) ? bK : bV;
    const float* __restrict__ Wh = W + (size_t)h * DD * DD;
    const float* __restrict__ bh = bias + h * DD;
    const int n0 = blockIdx.x * BN;

    const int tid  = threadIdx.x;
    const int lane = tid & 63;
    const int wave = tid >> 6;          // 0..7
    const int wm = wave & 3;            // 4 waves x 64 rows
    const int wn = wave >> 2;           // 2 waves x 32 cols

    // B gload_lds: wave handles 1KB instrs {wave, wave+8}; LDS dest linear,
    // global source pre-swizzled so a swizzled READ yields the right element.
    const int r0  = 4 * wave + (lane >> 4);
    const int cb0 = ((lane & 15) << 4) ^ ((r0 & 7) << 4);
    const float* gB0 = Wh + (size_t)(n0 + r0) * DD + (cb0 >> 2);
    const int r1  = 4 * (wave + 8) + (lane >> 4);
    const int cb1 = ((lane & 15) << 4) ^ ((r1 & 7) << 4);
    const float* gB1 = Wh + (size_t)(n0 + r1) * DD + (cb1 >> 2);
    char* ldsB0 = (char*)Bsm + wave * 1024;
    char* ldsB1 = (char*)Bsm + (wave + 8) * 1024;

    f32x4v acc[4][2];
    #pragma unroll
    for (int m = 0; m < 4; ++m)
        #pragma unroll
        for (int n = 0; n < 2; ++n)
            acc[m][n] = (f32x4v){0.f, 0.f, 0.f, 0.f};

    const int rrow = lane & 15;
    const int kg   = lane >> 4;

    for (int k0 = 0; k0 < DD; k0 += BK) {
        // async weight loads first (in flight during A staging)
        gload_lds16(gB0 + k0, ldsB0);
        gload_lds16(gB1 + k0, ldsB1);
        // A: 256 rows x 64 k, head-gathered fp32 -> fp16
        #pragma unroll
        for (int r = 0; r < 8; ++r) {
            int g   = r * 512 + tid;
            int row = g >> 4;
            int k   = (g & 15) * 4;
            const float4 v = *(const float4*)(x + (size_t)row * (SS * EE)
                                + ((k0 + k) >> 5) * EE + h * DH + (k & 31));
            f16x4 hv = { (_Float16)v.x, (_Float16)v.y, (_Float16)v.z, (_Float16)v.w };
            *(f16x4*)&Asm[row][k] = hv;
        }
        __syncthreads();

        #pragma unroll
        for (int ks = 0; ks < 2; ++ks) {
            const int kofs = ks * 32 + kg * 8;
            f16x8 af[4], bf[2];
            #pragma unroll
            for (int m = 0; m < 4; ++m)
                af[m] = *(const f16x8*)&Asm[wm * 64 + m * 16 + rrow][kofs];
            #pragma unroll
            for (int n = 0; n < 2; ++n) {
                const int o  = wn * 32 + n * 16 + rrow;
                const int by = o * 256 + ks * 128 + kg * 32;
                const int sw = (o & 7) << 4;
                const float4 lo = *(const float4*)((const char*)Bsm + (by ^ sw));
                const float4 hi = *(const float4*)((const char*)Bsm + ((by + 16) ^ sw));
                f16x8 bb;
                bb[0] = (_Float16)lo.x; bb[1] = (_Float16)lo.y;
                bb[2] = (_Float16)lo.z; bb[3] = (_Float16)lo.w;
                bb[4] = (_Float16)hi.x; bb[5] = (_Float16)hi.y;
                bb[6] = (_Float16)hi.z; bb[7] = (_Float16)hi.w;
                bf[n] = bb;
            }
            #pragma unroll
            for (int m = 0; m < 4; ++m)
                #pragma unroll
                for (int n = 0; n < 2; ++n)
                    acc[m][n] = __builtin_amdgcn_mfma_f32_16x16x32_f16(af[m], bf[n], acc[m][n], 0, 0, 0);
        }
        __syncthreads();
    }

    // epilogue: bias + fp16 store to ws qkv[p][h][b][o]
    __half* __restrict__ P = qkv + ((size_t)p * HH + h) * BB * DD;
    const int cg = lane >> 4;
    const int cl = lane & 15;
    #pragma unroll
    for (int n = 0; n < 2; ++n) {
        const int col = n0 + wn * 32 + n * 16 + cl;
        const float bv = bh[col];
        #pragma unroll
        for (int m = 0; m < 4; ++m) {
            const int row = wm * 64 + m * 16 + cg * 4;
            #pragma unroll
            for (int j = 0; j < 4; ++j)
                P[(size_t)(row + j) * DD + col] = (__half)(acc[m][n][j] + bv);
        }
    }
}

// One wave per (h,b), all-MFMA. St = K·Q^T (M=k, N=q) so softmax-over-q is a
// per-(m,j) reduce over 4 n-frags + 4-step shfl_xor butterfly in 16-lane groups.
// P (fp16, /sum and 1/sqrt(32) folded) -> LDS -> A-frags; V^T -> B-frags; PV MFMA.
__global__ __launch_bounds__(64)
void attn_kernel(const __half* __restrict__ qkv, float* __restrict__ out)
{
    __shared__ _Float16 A2[SS][68];   // attn[q][k]; 136B rows -> 2-way max
    __shared__ _Float16 Vt[DH][68];   // V^T [dd][k]

    const int hb = blockIdx.x;
    const int h  = hb >> 8;
    const int b  = hb & 255;
    const int lane = threadIdx.x;
    const int rrow = lane & 15;
    const int kg   = lane >> 4;

    const __half* __restrict__ Qp = qkv + ((size_t)(0 * HH + h) * BB + b) * DD;
    const __half* __restrict__ Kp = qkv + ((size_t)(1 * HH + h) * BB + b) * DD;
    const __half* __restrict__ Vp = qkv + ((size_t)(2 * HH + h) * BB + b) * DD;

    // V stage transposed: thread reads V row 'lane', scatters Vt[d][lane]
    {
        const f16x8* vr = (const f16x8*)(Vp + lane * DH);
        #pragma unroll
        for (int i = 0; i < 4; ++i) {
            f16x8 v = vr[i];
            #pragma unroll
            for (int j = 0; j < 8; ++j) Vt[i * 8 + j][lane] = v[j];
        }
    }

    // scores St[k][q] = K·Q^T, one MFMA per (m,n) since d=32=K
    f32x4v st[4][4];
    #pragma unroll
    for (int m = 0; m < 4; ++m)
        #pragma unroll
        for (int n = 0; n < 4; ++n)
            st[m][n] = (f32x4v){0.f, 0.f, 0.f, 0.f};
    f16x8 kf[4], qf[4];
    #pragma unroll
    for (int m = 0; m < 4; ++m)
        kf[m] = *(const f16x8*)(Kp + (m * 16 + rrow) * DH + kg * 8);
    #pragma unroll
    for (int n = 0; n < 4; ++n)
        qf[n] = *(const f16x8*)(Qp + (n * 16 + rrow) * DH + kg * 8);
    #pragma unroll
    for (int m = 0; m < 4; ++m)
        #pragma unroll
        for (int n = 0; n < 4; ++n)
            st[m][n] = __builtin_amdgcn_mfma_f32_16x16x32_f16(kf[m], qf[n], st[m][n], 0, 0, 0);

    // softmax over q (k = m*16 + kg*4 + j fixed per lane per (m,j))
    #pragma unroll
    for (int m = 0; m < 4; ++m) {
        #pragma unroll
        for (int j = 0; j < 4; ++j) {
            float v = fmaxf(fmaxf(st[m][0][j], st[m][1][j]),
                            fmaxf(st[m][2][j], st[m][3][j]));
            v = fmaxf(v, __shfl_xor(v, 1, 64));
            v = fmaxf(v, __shfl_xor(v, 2, 64));
            v = fmaxf(v, __shfl_xor(v, 4, 64));
            v = fmaxf(v, __shfl_xor(v, 8, 64));
            float s = 0.f;
            #pragma unroll
            for (int n = 0; n < 4; ++n) {
                float e = __expf(st[m][n][j] - v);
                st[m][n][j] = e; s += e;
            }
            s += __shfl_xor(s, 1, 64);
            s += __shfl_xor(s, 2, 64);
            s += __shfl_xor(s, 4, 64);
            s += __shfl_xor(s, 8, 64);
            const float inv = 0.17677669529663687f / s;   // fold 1/sqrt(32)
            #pragma unroll
            for (int n = 0; n < 4; ++n) st[m][n][j] *= inv;
        }
    }
    // write P[q][k] fp16; q = n*16+rrow, k = m*16 + kg*4 + j (j pairs packed)
    #pragma unroll
    for (int m = 0; m < 4; ++m)
        #pragma unroll
        for (int n = 0; n < 4; ++n) {
            f16x2 lo, hi;
            lo[0] = (_Float16)st[m][n][0]; lo[1] = (_Float16)st[m][n][1];
            hi[0] = (_Float16)st[m][n][2]; hi[1] = (_Float16)st[m][n][3];
            *(f16x2*)&A2[n * 16 + rrow][m * 16 + kg * 4 + 0] = lo;
            *(f16x2*)&A2[n * 16 + rrow][m * 16 + kg * 4 + 2] = hi;
        }
    __syncthreads();

    // PV: Z = A2 · V  (A2 rows feed A-frags, Vt rows feed B-frags)
    f32x4v zz[4][2];
    #pragma unroll
    for (int m2 = 0; m2 < 4; ++m2)
        #pragma unroll
        for (int n2 = 0; n2 < 2; ++n2)
            zz[m2][n2] = (f32x4v){0.f, 0.f, 0.f, 0.f};
    #pragma unroll
    for (int ks = 0; ks < 2; ++ks) {
        f16x8 pa[4], vb[2];
        #pragma unroll
        for (int m2 = 0; m2 < 4; ++m2)
            pa[m2] = *(const f16x8*)&A2[m2 * 16 + rrow][ks * 32 + kg * 8];
        #pragma unroll
        for (int n2 = 0; n2 < 2; ++n2)
            vb[n2] = *(const f16x8*)&Vt[n2 * 16 + rrow][ks * 32 + kg * 8];
        #pragma unroll
        for (int m2 = 0; m2 < 4; ++m2)
            #pragma unroll
            for (int n2 = 0; n2 < 2; ++n2)
                zz[m2][n2] = __builtin_amdgcn_mfma_f32_16x16x32_f16(pa[m2], vb[n2], zz[m2][n2], 0, 0, 0);
    }

    // out[b][q][h*32+dd]; q = m2*16 + kg*4 + j, dd = n2*16 + rrow
    float* __restrict__ op = out + (size_t)b * (SS * EE) + h * DH;
    #pragma unroll
    for (int m2 = 0; m2 < 4; ++m2)
        #pragma unroll
        for (int n2 = 0; n2 < 2; ++n2)
            #pragma unroll
            for (int j = 0; j < 4; ++j)
                op[(size_t)(m2 * 16 + kg * 4 + j) * EE + n2 * 16 + rrow] = zz[m2][n2][j];
}

extern "C" void kernel_launch(void* const* d_in, const int* in_sizes, int n_in,
                              void* d_out, int out_size, void* d_ws, size_t ws_size,
                              hipStream_t stream)
{
    const float* dec = (const float*)d_in[0];
    const float* enc = (const float*)d_in[1];
    const float* WQ  = (const float*)d_in[2];
    const float* bQ  = (const float*)d_in[3];
    const float* WK  = (const float*)d_in[4];
    const float* bK  = (const float*)d_in[5];
    const float* WV  = (const float*)d_in[6];
    const float* bV  = (const float*)d_in[7];
    __half* qkv = (__half*)d_ws;     // 3*8*256*2048 fp16 = 25.2 MB
    float* out = (float*)d_out;

    dim3 grid1(DD / BN, 1, 3 * HH);  // 32 x 1 x 24 = 768 blocks = 3/CU
    qkv_kernel<<<grid1, dim3(512, 1, 1), 0, stream>>>(dec, enc, WQ, bQ, WK, bK, WV, bV, qkv);
    attn_kernel<<<dim3(HH * BB, 1, 1), dim3(64, 1, 1), 0, stream>>>(qkv, out);
}